// Round 11
// baseline (264.958 us; speedup 1.0000x reference)
//
#include <hip/hip_runtime.h>
#include <hip/hip_bf16.h>

// ===================== Round 19: R11 structure x split-K 4 =====================
// R18 post-mortem: SIX loop structures all ~119-124us. The cross-kernel
// invariant: effective HBM BW 0.8-1.2 TB/s, scaling with STREAM COUNT not
// structure (R14's 2560 blocks: 1.46 TB/s, wasted on 2x FETCH by its bad
// reg-only path). Little's law: ~0.4MB chip-wide in flight — per-block A-issue
// is serialized (ISSUE waits prior arrival via STAGE dep; R9's deeper regs
// didn't move it). Untried cell of the matrix: MORE BLOCKS x GOOD STRUCTURE.
// This kernel = R11's gemm (122us, best; loop body byte-identical) with
// NKSPLIT 2->4: grid 2560, 8 blocks/CU by LDS(18.4KB)/VGPR(52), FETCH
// unchanged (~105MB: split-K partitions K), atomic partials 2->4.
// Predicted: hbm 1.2->1.7-2.2 TB/s, gemm 122->75-95us, WRITE ~77MB,
// absmax 0.001953125 (R14 validated 4-way split numerics). If ~120 again:
// plateau is structural -> roofline discussion / bf16-prepass last resort.

#define NFFT   512
#define HOP    128
#define KDIM   3084      // 257*6*2
#define KP     3136      // K padded to 49*64
#define NOUT   600
#define NP     640       // W rows padded (5*128)
#define BM     64
#define BN     128
#define BK     64
#define KSTEPS (KP / BK) // 49
#define LDA    72        // A LDS row stride in shorts (64+8)

#define NFRAG_K 98       // KP/32 k-chunks
#define FRAG_SH 512      // shorts per fragment (64 lanes x 8)
#define WTOT    ((size_t)(NP / 16) * NFRAG_K * FRAG_SH)  // 4.01 MB
#define NKSPLIT 4
#define GRIDB   (128 * 5 * NKSPLIT)   // 2560

typedef short s16x8 __attribute__((ext_vector_type(8)));
typedef float f32x4 __attribute__((ext_vector_type(4)));

static __device__ __forceinline__ unsigned short bf16_bits(float f) {
    __hip_bfloat16 b = __float2bfloat16(f);   // RNE - R4-verified path
    return *(unsigned short*)&b;
}

// LDS-only barrier: lgkmcnt(0) + s_barrier (proven R9-R11). Global loads stay
// in flight across it; ds ops complete before it.
static __device__ __forceinline__ void lds_barrier() {
    asm volatile("s_waitcnt lgkmcnt(0)" ::: "memory");
    __builtin_amdgcn_s_barrier();
    asm volatile("" ::: "memory");
}

// ---------------- W generation (fragment layout) + out zeroing ---------------
// Fragment (n16, kc) holds W[n16*16 + (l&15)][kc*32 + (l>>4)*8 + e] at
// shorts offset ((n16*98 + kc)*64 + l)*8 + e. (unchanged — passed R11/R13/R14/R17)
__global__ __launch_bounds__(256) void gen_W(unsigned short* __restrict__ Wt,
                                             float4* __restrict__ outZ,
                                             int nvec4) {
    __shared__ float costab[512];
    __shared__ __align__(16) unsigned short rowbuf[KP];   // 6272 B
    const int l   = blockIdx.x;     // 0..639  (row n = l)
    const int tid = threadIdx.x;
    const float w0 = 6.283185307179586f / 512.0f;

    // zero the output buffer in-kernel (atomic epilogue needs it)
    for (int i = blockIdx.x * 256 + tid; i < nvec4; i += NP * 256)
        outZ[i] = make_float4(0.f, 0.f, 0.f, 0.f);

    *(int4*)(rowbuf + tid * 8) = make_int4(0, 0, 0, 0);
    if (tid < 136) *(int4*)(rowbuf + (256 + tid) * 8) = make_int4(0, 0, 0, 0);
    costab[tid]       = __cosf((float)tid * w0);
    costab[tid + 256] = __cosf((float)(tid + 256) * w0);
    __syncthreads();

    if (l < NOUT) {
        const int p = l + 256;
        float env = 0.0f;
#pragma unroll
        for (int tt = 0; tt < 6; ++tt) {
            int m = p - HOP * tt;
            if (m >= 0 && m < NFFT) {
                float w = 0.5f - 0.5f * costab[m];
                env += w * w;
            }
        }
        const float inv = 1.0f / (512.0f * env);
        for (int f = tid; f <= 256; f += 256) {
            float cf = (f == 0 || f == 256) ? 1.0f : 2.0f;
#pragma unroll
            for (int t = 0; t < 6; ++t) {
                int n = p - HOP * t;
                if (n >= 0 && n < NFFT) {
                    float w = 0.5f - 0.5f * costab[n];
                    float scale = cf * w * inv;
                    int a = (f * n) & 511;
                    float c = costab[a];
                    float s = costab[(a + 384) & 511];
                    rowbuf[f * 12 + t * 2 + 0] = bf16_bits(scale * c);
                    rowbuf[f * 12 + t * 2 + 1] = bf16_bits(-scale * s);
                }
            }
        }
    }
    __syncthreads();

    const int n16 = l >> 4, r = l & 15;
    for (int u = tid; u < 392; u += 256) {
        const int kc = u >> 2, q = u & 3;
        int4 val = *(const int4*)(rowbuf + kc * 32 + q * 8);
        *(int4*)(Wt + (((size_t)n16 * NFRAG_K + kc) * 64 + q * 16 + r) * 8) = val;
    }
}

// ---------------- GEMM: out += X * W^T (split-K = 4) -------------------------
// 256 thr = 4 waves, wave tile 32(m) x 64(n); grid 2560 = 128mt x 5nt x 4k.
// Loop body BYTE-IDENTICAL to R11 (122us best): A reg-staged fp32->bf16 into
// double-buffered LDS, B direct global->reg from pre-swizzled W, one lgkm-only
// barrier per step. Only the K partition (2->4) and grid/swizzle changed.
__global__ __launch_bounds__(256, 4) void gemm_kernel(
        const float* __restrict__ X,           // fp32 [8192][3084]
        const unsigned short* __restrict__ Wt, // bf16 frags, WTOT shorts
        float* __restrict__ out) {             // fp32 [8192][600], pre-zeroed
    __shared__ __align__(16) unsigned short As[2 * BM * LDA];  // 18432 B

    const int tid = threadIdx.x;
    // XCD swizzle: the 20 blocks (5 nt x 4 kidx) of one mt share an XCD.
    const int bid  = blockIdx.x;           // 0..2559
    const int xcd  = bid & 7;
    const int rest = bid >> 3;             // 0..319
    const int mt   = xcd * 16 + rest / 20; // 0..127
    const int sub  = rest % 20;
    const int nt   = sub >> 2;             // 0..4
    const int kidx = sub & 3;              // 0..3
    const int mBase = mt * BM;
    const int nBase = nt * BN;
    const int sBeg  = (kidx * KSTEPS) / NKSPLIT;       // 0,12,24,36
    const int sEnd  = ((kidx + 1) * KSTEPS) / NKSPLIT; // 12,24,36,49

    const int lane = tid & 63;
    const int wave = tid >> 6;
    const int wm   = (wave & 1) * 32;
    const int wn   = (wave >> 1) * 64;
    const int lrow = lane & 15;
    const int quad = lane >> 4;

    // A staging map: 64 rows x 16 float4-cols; thread p-th unit:
    // row = (tid>>4)+16p, col4 = tid&15
    const int aRow = tid >> 4, aU = tid & 15;
    const float* aPtr = X + (size_t)(mBase + aRow) * KDIM + sBeg * BK + aU * 4;
    const int aColBase = aU * 4;
    const size_t aRowStride = (size_t)16 * KDIM;

    // B fragment base for this wave: n16 row-block = nt*8 + (wave>>1)*4 + j
    const int n16base = nt * 8 + (wave >> 1) * 4;
    const unsigned short* wB0 = Wt + (size_t)n16base * NFRAG_K * FRAG_SH
                                   + (size_t)lane * 8;

    f32x4 acc[2][4];
#pragma unroll
    for (int i = 0; i < 2; ++i)
#pragma unroll
        for (int j = 0; j < 4; ++j) acc[i][j] = (f32x4){0.f, 0.f, 0.f, 0.f};

#define ISSUE_A(AV, s)                                                         \
    {                                                                          \
        const int k0_ = (s) * BK;                                              \
        _Pragma("unroll")                                                      \
        for (int p = 0; p < 4; ++p) {                                          \
            AV[p] = make_float4(0.f, 0.f, 0.f, 0.f);                           \
            if (k0_ + aColBase < KDIM)                                         \
                AV[p] = *(const float4*)(aPtr + (size_t)((s) - sBeg) * BK +    \
                                         p * aRowStride);                      \
        }                                                                      \
    }

// load 4 B fragments (j=0..3) for k-chunk kc = 2*s + ks, straight into regs
#define ISSUE_B4(BV, s, ks)                                                    \
    {                                                                          \
        const size_t kc_ = (size_t)(2 * (s) + (ks));                           \
        _Pragma("unroll")                                                      \
        for (int j = 0; j < 4; ++j)                                            \
            BV[j] = *(const s16x8*)(const void*)(wB0 +                         \
                        ((size_t)j * NFRAG_K + kc_) * FRAG_SH);                \
    }

#define STAGE_A(AV, ABASE)                                                     \
    {                                                                          \
        _Pragma("unroll")                                                      \
        for (int p = 0; p < 4; ++p) {                                          \
            float4 v = AV[p];                                                  \
            unsigned long long pk = (unsigned long long)bf16_bits(v.x) |       \
                                    ((unsigned long long)bf16_bits(v.y) << 16) |\
                                    ((unsigned long long)bf16_bits(v.z) << 32) |\
                                    ((unsigned long long)bf16_bits(v.w) << 48); \
            *(unsigned long long*)(As + (ABASE) + (aRow + 16 * p) * LDA +      \
                                   aU * 4) = pk;                               \
        }                                                                      \
    }

#define COMPUTE_KS(ks, ABASE, BV)                                              \
    {                                                                          \
        const int koff = (ks) * 32 + quad * 8;                                 \
        s16x8 afr0 = *(const s16x8*)(const void*)(As + (ABASE) +               \
                         (wm + lrow) * LDA + koff);                            \
        s16x8 afr1 = *(const s16x8*)(const void*)(As + (ABASE) +               \
                         (wm + 16 + lrow) * LDA + koff);                       \
        _Pragma("unroll")                                                      \
        for (int j = 0; j < 4; ++j)                                            \
            acc[0][j] = __builtin_amdgcn_mfma_f32_16x16x32_bf16(               \
                afr0, BV[j], acc[0][j], 0, 0, 0);                              \
        _Pragma("unroll")                                                      \
        for (int j = 0; j < 4; ++j)                                            \
            acc[1][j] = __builtin_amdgcn_mfma_f32_16x16x32_bf16(               \
                afr1, BV[j], acc[1][j], 0, 0, 0);                              \
    }

    // ---- prologue: stage A(sBeg) into buf0; prefetch A(sBeg+1), B(sBeg)
    float4 avH[4];
    s16x8  bv0[4], bv1[4];
    ISSUE_A(avH, sBeg);
    ISSUE_B4(bv0, sBeg, 0);
    ISSUE_B4(bv1, sBeg, 1);
    STAGE_A(avH, 0);                 // vmcnt-waits avH only (counted)
    ISSUE_A(avH, sBeg + 1);
    lds_barrier();

    int ard = 0;                      // LDS read-buffer offset (shorts)
    for (int step = sBeg; step < sEnd; ++step) {
        const int awr = ard ^ (BM * LDA);
        // stage NEXT tile into the other buffer; reads of ard proceed below.
        if (step + 1 < sEnd) {
            STAGE_A(avH, awr);
            if (step + 2 < sEnd) ISSUE_A(avH, step + 2);
        }
        COMPUTE_KS(0, ard, bv0);
        if (step + 1 < sEnd) ISSUE_B4(bv0, step + 1, 0);
        COMPUTE_KS(1, ard, bv1);
        if (step + 1 < sEnd) ISSUE_B4(bv1, step + 1, 1);
        lds_barrier();                // single rendezvous per step
        ard = awr;
    }

#undef ISSUE_A
#undef ISSUE_B4
#undef STAGE_A
#undef COMPUTE_KS

    // ---- epilogue: H1 layout (n=lane&15, m=quad*4+reg), atomic accumulate
#pragma unroll
    for (int i = 0; i < 2; ++i) {
#pragma unroll
        for (int j = 0; j < 4; ++j) {
            int gn = nBase + wn + j * 16 + lrow;
            if (gn < NOUT) {
#pragma unroll
                for (int r = 0; r < 4; ++r) {
                    int gm = mBase + wm + i * 16 + quad * 4 + r;
                    atomicAdd(out + (size_t)gm * NOUT + gn, acc[i][j][r]);
                }
            }
        }
    }
}

extern "C" void kernel_launch(void* const* d_in, const int* in_sizes, int n_in,
                              void* d_out, int out_size, void* d_ws, size_t ws_size,
                              hipStream_t stream) {
    const float* X = (const float*)d_in[0];
    unsigned short* W = (unsigned short*)d_ws;   // bf16 fragment layout, 4.01 MB
    float* out = (float*)d_out;

    gen_W<<<dim3(NP), 256, 0, stream>>>(W, (float4*)d_out, out_size / 4);
    gemm_kernel<<<dim3(GRIDB), 256, 0, stream>>>(X, W, out);
}

// Round 12
// 259.468 us; speedup vs baseline: 1.0212x; 1.0212x over previous
//
#include <hip/hip_runtime.h>
#include <hip/hip_bf16.h>

// ===================== Round 20: 128x128 tile — halve L1 bytes per FLOP ========
// R19 post-mortem: 7 kernels fit ONE variable: VMEM bytes through the CU L1
// per unit compute. R11 runs at ~67 B/cy/CU == L1/TCP return ceiling (~64);
// R13/R14/R19 with more bytes/FLOP are proportionally slower; R17 (same bytes,
// 4x fewer VMEM instr) identical -> BYTES govern, not instructions. m97's
// 128^2 tile = 22 B/cy -> compute-bound at 36%. Fix: tile 64x128 -> 128x128.
// B bytes amortize over 2x M (48 KB/step for 2x FLOPs = 0.75x bytes/FLOP;
// fp32 A keeps it from 0.5x). Wave tile 64x64, acc[4][4]. All else = proven
// R11 machinery: reg-staged A pack -> dbuf LDS, lgkm-only barrier, B
// consume-then-reload from fragment W, split-K=4 (grid 1280 = 64mt x 5nt x 4k,
// main loop k<3072 unguarded), kc=96 tail on kidx=3, atomics + zero-pass.
// launch_bounds(256,3), est ~150 VGPR, LDS 36864 -> 3 blocks/CU.
// Predicted: gemm 122->65-85us, MfmaUtil 18-28%, WRITE ~77MB, FETCH 110-140MB,
// total 175-195us. Partial (~95) -> bf16-X prepass next. Null -> theory dead.

#define NFFT   512
#define HOP    128
#define KDIM   3084      // 257*6*2
#define KP     3136      // K padded to 49*64 — W layout only
#define NOUT   600
#define NP     640       // W rows padded (5*128)
#define BM     128
#define BN     128
#define BK     64
#define LDA    72        // A LDS row stride in shorts (64+8)
#define ABUF   (BM * LDA)   // shorts per A buffer (9216)

#define NFRAG_K 98       // KP/32 k-chunks
#define FRAG_SH 512      // shorts per fragment (64 lanes x 8)
#define WTOT    ((size_t)(NP / 16) * NFRAG_K * FRAG_SH)  // 4.01 MB
#define NKSPLIT 4
#define GRIDB   (64 * 5 * NKSPLIT)   // 1280

typedef short s16x8 __attribute__((ext_vector_type(8)));
typedef float f32x4 __attribute__((ext_vector_type(4)));

static __device__ __forceinline__ unsigned short bf16_bits(float f) {
    __hip_bfloat16 b = __float2bfloat16(f);   // RNE - R4-verified path
    return *(unsigned short*)&b;
}

// LDS-only barrier: lgkmcnt(0) + s_barrier (proven R9-R11/R18/R19). Global
// loads stay in flight across it; ds ops complete before it.
static __device__ __forceinline__ void lds_barrier() {
    asm volatile("s_waitcnt lgkmcnt(0)" ::: "memory");
    __builtin_amdgcn_s_barrier();
    asm volatile("" ::: "memory");
}

// ---------------- W generation (fragment layout) + out zeroing ---------------
// Fragment (n16, kc) holds W[n16*16 + (l&15)][kc*32 + (l>>4)*8 + e] at
// shorts offset ((n16*98 + kc)*64 + l)*8 + e. (unchanged — passed 5 rounds)
__global__ __launch_bounds__(256) void gen_W(unsigned short* __restrict__ Wt,
                                             float4* __restrict__ outZ,
                                             int nvec4) {
    __shared__ float costab[512];
    __shared__ __align__(16) unsigned short rowbuf[KP];   // 6272 B
    const int l   = blockIdx.x;     // 0..639  (row n = l)
    const int tid = threadIdx.x;
    const float w0 = 6.283185307179586f / 512.0f;

    // zero the output buffer in-kernel (atomic epilogue needs it)
    for (int i = blockIdx.x * 256 + tid; i < nvec4; i += NP * 256)
        outZ[i] = make_float4(0.f, 0.f, 0.f, 0.f);

    *(int4*)(rowbuf + tid * 8) = make_int4(0, 0, 0, 0);
    if (tid < 136) *(int4*)(rowbuf + (256 + tid) * 8) = make_int4(0, 0, 0, 0);
    costab[tid]       = __cosf((float)tid * w0);
    costab[tid + 256] = __cosf((float)(tid + 256) * w0);
    __syncthreads();

    if (l < NOUT) {
        const int p = l + 256;
        float env = 0.0f;
#pragma unroll
        for (int tt = 0; tt < 6; ++tt) {
            int m = p - HOP * tt;
            if (m >= 0 && m < NFFT) {
                float w = 0.5f - 0.5f * costab[m];
                env += w * w;
            }
        }
        const float inv = 1.0f / (512.0f * env);
        for (int f = tid; f <= 256; f += 256) {
            float cf = (f == 0 || f == 256) ? 1.0f : 2.0f;
#pragma unroll
            for (int t = 0; t < 6; ++t) {
                int n = p - HOP * t;
                if (n >= 0 && n < NFFT) {
                    float w = 0.5f - 0.5f * costab[n];
                    float scale = cf * w * inv;
                    int a = (f * n) & 511;
                    float c = costab[a];
                    float s = costab[(a + 384) & 511];
                    rowbuf[f * 12 + t * 2 + 0] = bf16_bits(scale * c);
                    rowbuf[f * 12 + t * 2 + 1] = bf16_bits(-scale * s);
                }
            }
        }
    }
    __syncthreads();

    const int n16 = l >> 4, r = l & 15;
    for (int u = tid; u < 392; u += 256) {
        const int kc = u >> 2, q = u & 3;
        int4 val = *(const int4*)(rowbuf + kc * 32 + q * 8);
        *(int4*)(Wt + (((size_t)n16 * NFRAG_K + kc) * 64 + q * 16 + r) * 8) = val;
    }
}

// ---------------- GEMM: out += X * W^T (128x128 tile, split-K = 4) -----------
// 256 thr = 4 waves; wave tile 64(m) x 64(n): wm2=(wave&1)*64, wn2=(wave>>1)*64.
// A: reg-staged fp32->bf16 into double-buffered LDS (128 rows x 64 k).
// B: direct global->reg fragments (consume-then-reload). One lgkm barrier/step.
// Main loop covers k<3072 (no guard); kc=96 tail on kidx==3; kc=97 zero-pad.
__global__ __launch_bounds__(256, 3) void gemm_kernel(
        const float* __restrict__ X,           // fp32 [8192][3084]
        const unsigned short* __restrict__ Wt, // bf16 frags, WTOT shorts
        float* __restrict__ out) {             // fp32 [8192][600], pre-zeroed
    __shared__ __align__(16) unsigned short As[2 * ABUF];  // 36864 B

    const int tid = threadIdx.x;
    // XCD swizzle: the 20 blocks (5 nt x 4 kidx) of one mt share an XCD.
    const int bid  = blockIdx.x;           // 0..1279
    const int xcd  = bid & 7;
    const int rest = bid >> 3;             // 0..159
    const int mt   = xcd * 8 + rest / 20;  // 0..63
    const int sub  = rest % 20;
    const int nt   = sub >> 2;             // 0..4
    const int kidx = sub & 3;              // 0..3
    const int mBase = mt * BM;
    const int nBase = nt * BN;
    const int sBeg  = kidx * 12;           // BK-steps: 12 each, 48 total
    const int sEnd  = sBeg + 12;

    const int lane = tid & 63;
    const int wave = tid >> 6;
    const int wm2  = (wave & 1) * 64;
    const int wn2  = (wave >> 1) * 64;
    const int lrow = lane & 15;
    const int quad = lane >> 4;

    // A staging map: 128 rows x 16 float4-cols; thread p-th unit (p=0..7):
    // row = (tid>>4)+16p, col4 = tid&15. Max k = 47*64+63 = 3071 < KDIM.
    const int aRowS = tid >> 4, aU = tid & 15;
    const float* aPtr = X + (size_t)(mBase + aRowS) * KDIM + sBeg * BK + aU * 4;
    const size_t aRowStride = (size_t)16 * KDIM;

    // B fragment base: n16 row-block = nt*8 + (wave>>1)*4 + j (j=0..3)
    const int n16base = nt * 8 + (wave >> 1) * 4;
    const unsigned short* wB0 = Wt + (size_t)n16base * NFRAG_K * FRAG_SH
                                   + (size_t)lane * 8;

    f32x4 acc[4][4];
#pragma unroll
    for (int i = 0; i < 4; ++i)
#pragma unroll
        for (int j = 0; j < 4; ++j) acc[i][j] = (f32x4){0.f, 0.f, 0.f, 0.f};

#define ISSUE_A(s)                                                             \
    {                                                                          \
        const float* b_ = aPtr + (size_t)((s) - sBeg) * BK;                    \
        _Pragma("unroll")                                                      \
        for (int p = 0; p < 8; ++p)                                            \
            avH[p] = *(const float4*)(b_ + (size_t)p * aRowStride);            \
    }

#define ISSUE_B4(BV, kc_)                                                      \
    {                                                                          \
        _Pragma("unroll")                                                      \
        for (int j = 0; j < 4; ++j)                                            \
            BV[j] = *(const s16x8*)(const void*)(wB0 +                         \
                        ((size_t)j * NFRAG_K + (size_t)(kc_)) * FRAG_SH);      \
    }

#define STAGE_A(AB)                                                            \
    {                                                                          \
        _Pragma("unroll")                                                      \
        for (int p = 0; p < 8; ++p) {                                          \
            float4 v = avH[p];                                                 \
            unsigned long long pk = (unsigned long long)bf16_bits(v.x) |       \
                                    ((unsigned long long)bf16_bits(v.y) << 16) |\
                                    ((unsigned long long)bf16_bits(v.z) << 32) |\
                                    ((unsigned long long)bf16_bits(v.w) << 48); \
            *(unsigned long long*)(As + (AB) + (aRowS + 16 * p) * LDA +        \
                                   aU * 4) = pk;                               \
        }                                                                      \
    }

#define COMPUTE_KS(AB, ks, BV)                                                 \
    {                                                                          \
        const int koff = (ks) * 32 + quad * 8;                                 \
        _Pragma("unroll")                                                      \
        for (int i = 0; i < 4; ++i) {                                          \
            s16x8 afr = *(const s16x8*)(const void*)(As + (AB) +               \
                            (wm2 + i * 16 + lrow) * LDA + koff);               \
            _Pragma("unroll")                                                  \
            for (int j = 0; j < 4; ++j)                                        \
                acc[i][j] = __builtin_amdgcn_mfma_f32_16x16x32_bf16(           \
                    afr, BV[j], acc[i][j], 0, 0, 0);                           \
        }                                                                      \
    }

    // ---- prologue: stage A(sBeg) into buf0; prefetch A(sBeg+1), B(kc0,kc0+1)
    float4 avH[8];
    s16x8  bv0[4], bv1[4];
    ISSUE_A(sBeg);
    ISSUE_B4(bv0, 2 * sBeg);
    ISSUE_B4(bv1, 2 * sBeg + 1);
    STAGE_A(0);                      // vmcnt-waits avH only (counted)
    ISSUE_A(sBeg + 1);
    lds_barrier();

    int ard = 0;                      // LDS read-buffer offset (shorts)
    for (int step = sBeg; step < sEnd; ++step) {
        const int awr = ard ^ ABUF;
        // stage NEXT tile into the other buffer; reads of ard proceed below.
        if (step + 1 < sEnd) {
            STAGE_A(awr);
            if (step + 2 < sEnd) ISSUE_A(step + 2);
        }
        COMPUTE_KS(ard, 0, bv0);
        if (step + 1 < sEnd) ISSUE_B4(bv0, 2 * (step + 1));
        COMPUTE_KS(ard, 1, bv1);
        if (step + 1 < sEnd) ISSUE_B4(bv1, 2 * (step + 1) + 1);
        lds_barrier();                // single rendezvous per step
        ard = awr;
    }

    // ---- K tail: kc = 96 (k 3072..3103, guard vs KDIM=3084), kidx==3 only.
    if (kidx == 3) {
        const int kb = 96 * 32 + quad * 8;
        ISSUE_B4(bv0, 96);
#pragma unroll
        for (int i = 0; i < 4; ++i) {
            const float* aR = X + (size_t)(mBase + wm2 + i * 16 + lrow) * KDIM;
            s16x8 af;
#pragma unroll
            for (int e = 0; e < 8; ++e) {
                const int k = kb + e;
                af[e] = (short)bf16_bits(k < KDIM ? aR[k] : 0.f);
            }
#pragma unroll
            for (int j = 0; j < 4; ++j)
                acc[i][j] = __builtin_amdgcn_mfma_f32_16x16x32_bf16(
                    af, bv0[j], acc[i][j], 0, 0, 0);
        }
    }

#undef ISSUE_A
#undef ISSUE_B4
#undef STAGE_A
#undef COMPUTE_KS

    // ---- epilogue: H1 layout (n=lane&15, m=quad*4+reg), atomic accumulate
#pragma unroll
    for (int i = 0; i < 4; ++i) {
#pragma unroll
        for (int j = 0; j < 4; ++j) {
            int gn = nBase + wn2 + j * 16 + lrow;
            if (gn < NOUT) {
#pragma unroll
                for (int r = 0; r < 4; ++r) {
                    int gm = mBase + wm2 + i * 16 + quad * 4 + r;
                    atomicAdd(out + (size_t)gm * NOUT + gn, acc[i][j][r]);
                }
            }
        }
    }
}

extern "C" void kernel_launch(void* const* d_in, const int* in_sizes, int n_in,
                              void* d_out, int out_size, void* d_ws, size_t ws_size,
                              hipStream_t stream) {
    const float* X = (const float*)d_in[0];
    unsigned short* W = (unsigned short*)d_ws;   // bf16 fragment layout, 4.01 MB
    float* out = (float*)d_out;

    gen_W<<<dim3(NP), 256, 0, stream>>>(W, (float4*)d_out, out_size / 4);
    gemm_kernel<<<dim3(GRIDB), 256, 0, stream>>>(X, W, out);
}